// Round 2
// baseline (2521.897 us; speedup 1.0000x reference)
//
#include <hip/hip_runtime.h>
#include <hip/hip_bf16.h>
#include <cmath>
#include <cstdint>

#define NPT 4095      // nodes per tree
#define NT  32760     // total nodes (8 trees)
#define FD  512       // hidden/feature dim

using bf16 = __hip_bfloat16;
using bf8v = __attribute__((ext_vector_type(8))) short;   // 8 bf16 (4 VGPRs)
using us8v = __attribute__((ext_vector_type(8))) unsigned short;
using f4v  = __attribute__((ext_vector_type(4))) float;   // MFMA accumulator

__device__ __forceinline__ float b2f(bf16 x){ return __bfloat162float(x); }
__device__ __forceinline__ bf16  f2b(float x){ return __float2bfloat16(x); }
__device__ __forceinline__ float sigf(float x){ return 1.f/(1.f + expf(-x)); }
__device__ __forceinline__ float us2f(unsigned short u){ union{unsigned int i; float f;} v; v.i = ((unsigned)u)<<16; return v.f; }
__device__ __forceinline__ unsigned short f2us(float f){ bf16 b = __float2bfloat16(f); union{bf16 b; unsigned short u;} v; v.b = b; return v.u; }

// async 16B global -> LDS (dest = wave-uniform base + lane*16)
__device__ __forceinline__ void gload_lds16(const bf16* g, bf16* l){
  __builtin_amdgcn_global_load_lds(
    (const __attribute__((address_space(1))) unsigned int*)g,
    (__attribute__((address_space(3))) unsigned int*)l, 16, 0, 0);
}

// ---------------- elementwise / gather kernels (8 elem/thread) ----------------

__global__ void cvt_b16(bf16* __restrict__ dst, const float* __restrict__ src, int n8){
  int e = blockIdx.x*256 + threadIdx.x;     // one per 8 elements
  if (e >= n8) return;
  const float4* s = (const float4*)(src + (size_t)e*8);
  float4 a = s[0], b = s[1];
  us8v o = { f2us(a.x), f2us(a.y), f2us(a.z), f2us(a.w),
             f2us(b.x), f2us(b.y), f2us(b.z), f2us(b.w) };
  *(us8v*)(dst + (size_t)e*8) = o;
}

// copy one 512x512 fp32 matrix into packed bf16 dst at (ro,co), row stride dstK
__global__ void pack_w(bf16* __restrict__ dst, int dstK, int ro, int co, const float* __restrict__ src){
  int e = blockIdx.x*256 + threadIdx.x;      // 512*512/8 = 32768 chunks
  int r = e >> 6, c8 = e & 63;
  const float4* s = (const float4*)(src + (size_t)r*512 + c8*8);
  float4 a = s[0], b = s[1];
  us8v o = { f2us(a.x), f2us(a.y), f2us(a.z), f2us(a.w),
             f2us(b.x), f2us(b.y), f2us(b.z), f2us(b.w) };
  *(us8v*)(dst + (size_t)(ro + r)*dstK + co + c8*8) = o;
}

// h[leaf] = (1-z)*tanh_c  (z, t stored fp32 by leaf GEMM)
__global__ void leaf_combine(bf16* __restrict__ h_b, const float* __restrict__ zb, const float* __restrict__ tb){
  int e = blockIdx.x*256 + threadIdx.x;      // 16384*512/8 chunks
  int m = e >> 6, c8 = e & 63;
  int tree = m >> 11, pos = m & 2047;
  size_t node = (size_t)tree*NPT + pos;
  size_t off = (size_t)m*FD + c8*8;
  const float4* zp = (const float4*)(zb + off);
  const float4* tp = (const float4*)(tb + off);
  float4 z0 = zp[0], z1 = zp[1], t0 = tp[0], t1 = tp[1];
  us8v o = { f2us((1.f-z0.x)*t0.x), f2us((1.f-z0.y)*t0.y), f2us((1.f-z0.z)*t0.z), f2us((1.f-z0.w)*t0.w),
             f2us((1.f-z1.x)*t1.x), f2us((1.f-z1.y)*t1.y), f2us((1.f-z1.z)*t1.z), f2us((1.f-z1.w)*t1.w) };
  *(us8v*)(h_b + node*FD + c8*8) = o;
}

// s_b[m,:] = h[son0] + h[son1] for father m of this level
__global__ void hsum_k(bf16* __restrict__ s_b, const bf16* __restrict__ h_b, int son_start, int l2f, int n8){
  int e = blockIdx.x*256 + threadIdx.x;      // Mf*64 chunks
  if (e >= n8) return;
  int m = e >> 6, c8 = e & 63;
  int tree = m >> l2f, pos = m & ((1<<l2f)-1);
  size_t s0 = ((size_t)tree*NPT + son_start + 2*pos)*FD + c8*8;
  us8v a = *(const us8v*)(h_b + s0);
  us8v b = *(const us8v*)(h_b + s0 + FD);
  us8v o;
  #pragma unroll
  for (int i = 0; i < 8; ++i) o[i] = f2us(us2f(a[i]) + us2f(b[i]));
  *(us8v*)(s_b + (size_t)m*FD + c8*8) = o;
}

// s_b[m,:] = hd[father(m)] for son m of this level
__global__ void hfa_k(bf16* __restrict__ s_b, const bf16* __restrict__ hd_b, int fa_start, int l2s, int n8){
  int e = blockIdx.x*256 + threadIdx.x;      // Ms*64 chunks
  if (e >= n8) return;
  int m = e >> 6, c8 = e & 63;
  int tree = m >> l2s, pos = m & ((1<<l2s)-1);
  size_t f = ((size_t)tree*NPT + fa_start + (pos >> 1))*FD + c8*8;
  *(us8v*)(s_b + (size_t)m*FD + c8*8) = *(const us8v*)(hd_b + f);
}

// rh = bf16(r * s)
__global__ void rh_k(bf16* __restrict__ rh, const float* __restrict__ r, const bf16* __restrict__ s, int n8){
  int e = blockIdx.x*256 + threadIdx.x;
  if (e >= n8) return;
  size_t off = (size_t)e*8;
  const float4* rp = (const float4*)(r + off);
  float4 r0 = rp[0], r1 = rp[1];
  us8v sv = *(const us8v*)(s + off);
  us8v o = { f2us(r0.x*us2f(sv[0])), f2us(r0.y*us2f(sv[1])), f2us(r0.z*us2f(sv[2])), f2us(r0.w*us2f(sv[3])),
             f2us(r1.x*us2f(sv[4])), f2us(r1.y*us2f(sv[5])), f2us(r1.z*us2f(sv[6])), f2us(r1.w*us2f(sv[7])) };
  *(us8v*)(rh + off) = o;
}

// hd[root] = h[root]
__global__ void roots_k(bf16* __restrict__ hd, const bf16* __restrict__ h){
  int e = blockIdx.x*256 + threadIdx.x;      // 8*64 chunks
  int t = e >> 6, c8 = e & 63;
  size_t off = ((size_t)t*NPT + 4094)*FD + c8*8;
  *(us8v*)(hd + off) = *(const us8v*)(h + off);
}

// ---------------- 128x128-tile MFMA GEMM with global_load_lds staging ----------------
// Y[m,n] = sum_k Ain[m,k] * Wp[n,k],  K in {512,1024}, N = gridDim.y*128
// Ain row m: k<512 -> A0[node(m)*512 + k]  (node = tree*NPT + a_start + (m & amask))
//            k>=512 -> A1[m*512 + (k-512)]
// modes: 0 leaf (n<512: sig->outA fp32 ; n>=512: tanh->outB fp32)
//        1 gates (n<512: sig(v+bias0[n])->outA ; else sig(v+bias1[n-512])->outB)
//        2 combine (N=512): c=tanh(v); h=z*s+(1-z)*c; outH[onode(m)*512+n]=bf16(h)
//        4 out (N=512): outF[m*512+n] = v + bias0[n] + bias1[n]
__global__ __launch_bounds__(256) void gemm_k(
    const bf16* __restrict__ A0, const bf16* __restrict__ A1,
    const bf16* __restrict__ Wp, int M, int K,
    int a_start, int a_log2, int o_start, int o_log2,
    const float* __restrict__ bias0, const float* __restrict__ bias1,
    const float* __restrict__ zbuf, const bf16* __restrict__ sbuf,
    float* __restrict__ outA, float* __restrict__ outB,
    bf16* __restrict__ outH, float* __restrict__ outF, int mode)
{
  __shared__ bf16 As[128*32];
  __shared__ bf16 Bs[128*32];

  const int t    = threadIdx.x;
  const int lane = t & 63;
  const int wid  = t >> 6;
  const int wr = wid >> 1, wc = wid & 1;          // wave tile 64x64 at (wr*64, wc*64)
  const int lr   = lane & 15;
  const int quad = lane >> 4;
  const int m_blk = blockIdx.x * 128;
  const int n_blk = blockIdx.y * 128;
  const int Mm1 = M - 1;
  const int amask = (1 << a_log2) - 1;
  const int wuni = (t & ~63);                      // wave-uniform thread base

  f4v acc[4][4] = {};

  for (int k0 = 0; k0 < K; k0 += 32){
    // ---- stage A tile (128 rows x 32 k), row-major stride 32 ----
    #pragma unroll
    for (int p = 0; p < 2; ++p){
      int c = p*256 + t;                  // 16B chunk id: row = c>>2, kchunk = c&3
      int r = m_blk + (c >> 2); if (r > Mm1) r = Mm1;
      int kk = k0 + (c & 3)*8;
      const bf16* src;
      if (k0 < 512){
        int tree = r >> a_log2, pos = r & amask;
        src = A0 + ((long)tree*NPT + a_start + pos)*FD + kk;
      } else {
        src = A1 + (long)r*FD + (kk - 512);
      }
      gload_lds16(src, &As[(size_t)(p*256 + wuni)*8]);
    }
    // ---- stage B tile (128 n-rows x 32 k) ----
    #pragma unroll
    for (int p = 0; p < 2; ++p){
      int c = p*256 + t;
      int n = n_blk + (c >> 2);
      int kk = k0 + (c & 3)*8;
      gload_lds16(Wp + (long)n*K + kk, &Bs[(size_t)(p*256 + wuni)*8]);
    }
    __syncthreads();

    bf8v af[4], bf[4];
    #pragma unroll
    for (int i = 0; i < 4; ++i){
      af[i] = *(const bf8v*)&As[(wr*64 + i*16 + lr)*32 + quad*8];
      bf[i] = *(const bf8v*)&Bs[(wc*64 + i*16 + lr)*32 + quad*8];
    }
    #pragma unroll
    for (int i = 0; i < 4; ++i)
      #pragma unroll
      for (int j = 0; j < 4; ++j)
        acc[i][j] = __builtin_amdgcn_mfma_f32_16x16x32_bf16(af[i], bf[j], acc[i][j], 0, 0, 0);
    __syncthreads();
  }

  // ---- epilogue ----
  const int omask = (1 << o_log2) - 1;
  #pragma unroll
  for (int mt = 0; mt < 4; ++mt){
    int rbase = m_blk + wr*64 + mt*16 + quad*4;   // C/D: row=(lane>>4)*4+i, col=lane&15
    #pragma unroll
    for (int nt = 0; nt < 4; ++nt){
      int n = n_blk + wc*64 + nt*16 + lr;
      #pragma unroll
      for (int i = 0; i < 4; ++i){
        int row = rbase + i;
        if (row >= M) continue;
        float v = acc[mt][nt][i];
        if (mode == 0){
          if (n < 512) outA[(size_t)row*FD + n] = sigf(v);
          else         outB[(size_t)row*FD + (n-512)] = tanhf(v);
        } else if (mode == 1){
          if (n < 512) outA[(size_t)row*FD + n] = sigf(v + bias0[n]);
          else         outB[(size_t)row*FD + (n-512)] = sigf(v + bias1[n-512]);
        } else if (mode == 2){
          float c = tanhf(v);
          float z = zbuf[(size_t)row*FD + n];
          float s = b2f(sbuf[(size_t)row*FD + n]);
          float h = z*s + (1.f - z)*c;
          int tree = row >> o_log2, pos = row & omask;
          long node = (long)tree*NPT + o_start + pos;
          outH[node*FD + n] = f2b(h);
        } else { // mode 4
          outF[(size_t)row*FD + n] = v + bias0[n] + bias1[n];
        }
      }
    }
  }
}

// ---------------- host launcher ----------------

extern "C" void kernel_launch(void* const* d_in, const int* in_sizes, int n_in,
                              void* d_out, int out_size, void* d_ws, size_t ws_size,
                              hipStream_t stream)
{
  const float* feat = (const float*)d_in[0];
  const float* Wh   = (const float*)d_in[1];
  const float* Wz   = (const float*)d_in[2];
  const float* Wr   = (const float*)d_in[3];
  const float* Uh   = (const float*)d_in[4];
  const float* Uz   = (const float*)d_in[5];
  const float* bUz  = (const float*)d_in[6];
  const float* Ur   = (const float*)d_in[7];
  const float* bUr  = (const float*)d_in[8];
  const float* Whd  = (const float*)d_in[9];
  const float* Wzd  = (const float*)d_in[10];
  const float* Wrd  = (const float*)d_in[11];
  const float* Uhd  = (const float*)d_in[12];
  const float* Uzd  = (const float*)d_in[13];
  const float* bUzd = (const float*)d_in[14];
  const float* Urd  = (const float*)d_in[15];
  const float* bUrd = (const float*)d_in[16];
  const float* W1   = (const float*)d_in[17];
  const float* b1   = (const float*)d_in[18];
  const float* W2   = (const float*)d_in[19];
  const float* b2   = (const float*)d_in[20];
  float* out = (float*)d_out;

  int starts[12], szs[12];
  { int s = 0, sz = 2048; for (int l = 0; l < 12; ++l){ starts[l] = s; szs[l] = sz; s += sz; sz >>= 1; } }

  char* p = (char*)d_ws;
  auto take = [&](size_t b)->char*{ char* q = p; p += (b + 255) & ~(size_t)255; return q; };
  bf16* featb = (bf16*)take((size_t)NT*FD*2);
  bf16* h_b   = (bf16*)take((size_t)NT*FD*2);
  bf16* hd_b  = (bf16*)take((size_t)NT*FD*2);
  bf16* Wl    = (bf16*)take((size_t)1024*512*2);   // [Wz ; Wh], K=512
  bf16* Wzr_u = (bf16*)take((size_t)1024*1024*2);  // [[Wz|Uz];[Wr|Ur]], K=1024
  bf16* Whu   = (bf16*)take((size_t)512*1024*2);   // [Wh|Uh], K=1024
  bf16* Wzr_d = (bf16*)take((size_t)1024*1024*2);
  bf16* Whu_d = (bf16*)take((size_t)512*1024*2);
  bf16* Wout  = (bf16*)take((size_t)512*1024*2);   // [W1|W2], K=1024
  float* z_b  = (float*)take((size_t)16384*512*4);
  float* r_b  = (float*)take((size_t)16384*512*4);
  bf16* s_b   = (bf16*)take((size_t)16384*512*2);  // hsum / hfa
  bf16* rh_b  = (bf16*)take((size_t)16384*512*2);
  if ((size_t)(p - (char*)d_ws) > ws_size) return;

  // --- stage inputs ---
  cvt_b16<<<(NT*FD/8 + 255)/256, 256, 0, stream>>>(featb, feat, NT*FD/8);
  auto pk = [&](bf16* dst, int dk, int ro, int co, const float* src){
    pack_w<<<128, 256, 0, stream>>>(dst, dk, ro, co, src);
  };
  pk(Wl,   512,   0,   0, Wz);  pk(Wl,   512, 512,   0, Wh);
  pk(Wzr_u,1024,  0,   0, Wz);  pk(Wzr_u,1024,  0, 512, Uz);
  pk(Wzr_u,1024,512,   0, Wr);  pk(Wzr_u,1024,512, 512, Ur);
  pk(Whu,  1024,  0,   0, Wh);  pk(Whu,  1024,  0, 512, Uh);
  pk(Wzr_d,1024,  0,   0, Wzd); pk(Wzr_d,1024,  0, 512, Uzd);
  pk(Wzr_d,1024,512,   0, Wrd); pk(Wzr_d,1024,512, 512, Urd);
  pk(Whu_d,1024,  0,   0, Whd); pk(Whu_d,1024,  0, 512, Uhd);
  pk(Wout, 1024,  0,   0, W1);  pk(Wout, 1024,  0, 512, W2);

  auto gemm = [&](const bf16* A0, const bf16* A1, const bf16* Wp, int M, int N, int K,
                  int a_start, int a_log2, int o_start, int o_log2,
                  const float* bias0, const float* bias1,
                  const float* zbuf, const bf16* sbuf,
                  float* outA, float* outB, bf16* outH, float* outF, int mode){
    dim3 g((M + 127)/128, N/128);
    gemm_k<<<g, 256, 0, stream>>>(A0, A1, Wp, M, K, a_start, a_log2, o_start, o_log2,
                                  bias0, bias1, zbuf, sbuf, outA, outB, outH, outF, mode);
  };

  // --- leaves: z=sig(xWz), t=tanh(xWh); h = (1-z)*t ---
  gemm(featb, nullptr, Wl, 16384, 1024, 512, 0, 11, 0, 0,
       nullptr, nullptr, nullptr, nullptr, z_b, r_b, nullptr, nullptr, 0);
  leaf_combine<<<16384*64/256, 256, 0, stream>>>(h_b, z_b, r_b);

  // --- bottom-up ---
  for (int l = 0; l < 11; ++l){
    int Mf = 8*szs[l+1];
    int l2f = 10 - l;
    int n8 = Mf*64;
    hsum_k<<<(n8 + 255)/256, 256, 0, stream>>>(s_b, h_b, starts[l], l2f, n8);
    gemm(featb, s_b, Wzr_u, Mf, 1024, 1024, starts[l+1], l2f, 0, 0,
         bUz, bUr, nullptr, nullptr, z_b, r_b, nullptr, nullptr, 1);
    rh_k<<<(n8 + 255)/256, 256, 0, stream>>>(rh_b, r_b, s_b, n8);
    gemm(featb, rh_b, Whu, Mf, 512, 1024, starts[l+1], l2f, starts[l+1], l2f,
         nullptr, nullptr, z_b, s_b, nullptr, nullptr, h_b, nullptr, 2);
  }

  // --- roots: hd = h ---
  roots_k<<<2, 256, 0, stream>>>(hd_b, h_b);

  // --- top-down ---
  for (int l = 10; l >= 0; --l){
    int Ms = 8*szs[l];
    int l2s = 11 - l;
    int n8 = Ms*64;
    hfa_k<<<(n8 + 255)/256, 256, 0, stream>>>(s_b, hd_b, starts[l+1], l2s, n8);
    gemm(featb, s_b, Wzr_d, Ms, 1024, 1024, starts[l], l2s, 0, 0,
         bUzd, bUrd, nullptr, nullptr, z_b, r_b, nullptr, nullptr, 1);
    rh_k<<<(n8 + 255)/256, 256, 0, stream>>>(rh_b, r_b, s_b, n8);
    gemm(featb, rh_b, Whu_d, Ms, 512, 1024, starts[l], l2s, starts[l], l2s,
         nullptr, nullptr, z_b, s_b, nullptr, nullptr, hd_b, nullptr, 2);
  }

  // --- output: [h|hd] @ [W1|W2].T + b1 + b2 ---
  gemm(h_b, hd_b, Wout, NT, 512, 1024, 0, 26, 0, 26,
       b1, b2, nullptr, nullptr, nullptr, nullptr, nullptr, out, 4);
}

// Round 3
// 1640.905 us; speedup vs baseline: 1.5369x; 1.5369x over previous
//
#include <hip/hip_runtime.h>
#include <hip/hip_bf16.h>
#include <cmath>
#include <cstdint>

#define NPT 4095      // nodes per tree
#define NT  32760     // total nodes (8 trees)
#define FD  512       // hidden/feature dim

using bf16 = __hip_bfloat16;
using bf8v = __attribute__((ext_vector_type(8))) short;   // 8 bf16 (4 VGPRs)
using us8v = __attribute__((ext_vector_type(8))) unsigned short;
using f4v  = __attribute__((ext_vector_type(4))) float;   // MFMA accumulator

__device__ __forceinline__ float b2f(bf16 x){ return __bfloat162float(x); }
__device__ __forceinline__ bf16  f2b(float x){ return __float2bfloat16(x); }
__device__ __forceinline__ float sigf(float x){ return 1.f/(1.f + expf(-x)); }
__device__ __forceinline__ float us2f(unsigned short u){ union{unsigned int i; float f;} v; v.i = ((unsigned)u)<<16; return v.f; }
__device__ __forceinline__ unsigned short f2us(float f){ union{bf16 b; unsigned short u;} v; v.b = __float2bfloat16(f); return v.u; }

// async 16B global -> LDS (dest = wave-uniform base + lane*16)
__device__ __forceinline__ void gload_lds16(const bf16* g, bf16* l){
  __builtin_amdgcn_global_load_lds(
    (const __attribute__((address_space(1))) unsigned int*)g,
    (__attribute__((address_space(3))) unsigned int*)l, 16, 0, 0);
}

// ---------------- staging kernels ----------------

__global__ void cvt_b16(bf16* __restrict__ dst, const float* __restrict__ src, int n8){
  int e = blockIdx.x*256 + threadIdx.x;
  if (e >= n8) return;
  const float4* s = (const float4*)(src + (size_t)e*8);
  float4 a = s[0], b = s[1];
  us8v o = { f2us(a.x), f2us(a.y), f2us(a.z), f2us(a.w),
             f2us(b.x), f2us(b.y), f2us(b.z), f2us(b.w) };
  *(us8v*)(dst + (size_t)e*8) = o;
}

struct PackArgs { const float* s[16]; bf16* d[16]; int dk[16]; int ro[16]; int co[16]; };
__global__ void pack_all(PackArgs pa){
  int idx = blockIdx.x >> 7;               // 128 blocks per 512x512 matrix
  int e = (blockIdx.x & 127)*256 + threadIdx.x;   // 32768 8-elem chunks
  int r = e >> 6, c8 = e & 63;
  const float4* s = (const float4*)(pa.s[idx] + (size_t)r*512 + c8*8);
  float4 a = s[0], b = s[1];
  us8v o = { f2us(a.x), f2us(a.y), f2us(a.z), f2us(a.w),
             f2us(b.x), f2us(b.y), f2us(b.z), f2us(b.w) };
  *(us8v*)(pa.d[idx] + (size_t)(pa.ro[idx] + r)*pa.dk[idx] + pa.co[idx] + c8*8) = o;
}

// leaves: h = (1-z)*t for row pair (2j, 2j+1); also s0[j] = h0 + h1
__global__ void leaf_combine(bf16* __restrict__ h_b, bf16* __restrict__ s0,
                             const bf16* __restrict__ zb, const bf16* __restrict__ tb){
  int e = blockIdx.x*256 + threadIdx.x;    // 8192*64 chunks
  int j = e >> 6, c8 = e & 63;
  int m0 = 2*j;
  int tree = m0 >> 11, pos = m0 & 2047;
  size_t node = (size_t)tree*NPT + pos;
  size_t i0 = (size_t)m0*FD + c8*8;
  us8v z0 = *(const us8v*)(zb + i0), t0 = *(const us8v*)(tb + i0);
  us8v z1 = *(const us8v*)(zb + i0 + FD), t1 = *(const us8v*)(tb + i0 + FD);
  us8v h0, h1, sv;
  #pragma unroll
  for (int i = 0; i < 8; ++i){
    float a = (1.f - us2f(z0[i])) * us2f(t0[i]);
    float b = (1.f - us2f(z1[i])) * us2f(t1[i]);
    h0[i] = f2us(a); h1[i] = f2us(b); sv[i] = f2us(a + b);
  }
  *(us8v*)(h_b + node*FD + c8*8) = h0;
  *(us8v*)(h_b + (node+1)*FD + c8*8) = h1;
  *(us8v*)(s0 + (size_t)j*FD + c8*8) = sv;
}

// roots: hd[root]=h[root]; sA[2t]=sA[2t+1]=h[root]
__global__ void roots_k(bf16* __restrict__ hd, bf16* __restrict__ sA, const bf16* __restrict__ h){
  int e = blockIdx.x*256 + threadIdx.x;    // 512
  int t = e >> 6, c8 = e & 63;
  size_t off = ((size_t)t*NPT + 4094)*FD + c8*8;
  us8v v = *(const us8v*)(h + off);
  *(us8v*)(hd + off) = v;
  *(us8v*)(sA + (size_t)(2*t)*FD + c8*8) = v;
  *(us8v*)(sA + (size_t)(2*t+1)*FD + c8*8) = v;
}

// ---------------- shared epilogue ----------------
// modes: 0 leaf (n<512: bf16 sig->o0; else bf16 tanh->o1)
//        1 gates (n<512: bf16 sig(v+bias0[n])->o0(z); else r=sig(v+bias1[n-512]);
//                 o1(rh)[row,n-512] = bf16(r * sb[row,n-512]))
//        2 cand  (c=tanh(v); h=z*s+(1-z)*c; hO[node,n]=h;
//                 smode1: sN[row>>1,n]=h_even+h_odd ; smode2: sN[2row,n]=sN[2row+1,n]=h)
//        4 out   (outF[row,n] = v + bias0[n] + bias1[n])
__device__ __forceinline__ void epi4(
    const f4v& a, int rbase, int n, int M, int mode,
    const float* __restrict__ bias0, const float* __restrict__ bias1,
    const bf16* __restrict__ zb, const bf16* __restrict__ sb,
    bf16* __restrict__ o0, bf16* __restrict__ o1,
    bf16* __restrict__ hO, float* __restrict__ outF,
    int o_start, int o_log2, bf16* __restrict__ sN, int smode)
{
  if (rbase >= M) return;
  if (mode == 0){
    #pragma unroll
    for (int i = 0; i < 4; ++i){
      int row = rbase + i; if (row >= M) break;
      float v = a[i];
      if (n < 512) o0[(size_t)row*FD + n] = f2b(sigf(v));
      else         o1[(size_t)row*FD + (n-512)] = f2b(tanhf(v));
    }
  } else if (mode == 1){
    #pragma unroll
    for (int i = 0; i < 4; ++i){
      int row = rbase + i; if (row >= M) break;
      float v = a[i];
      if (n < 512){
        o0[(size_t)row*FD + n] = f2b(sigf(v + bias0[n]));
      } else {
        float r = sigf(v + bias1[n-512]);
        size_t off = (size_t)row*FD + (n-512);
        o1[off] = f2b(r * b2f(sb[off]));
      }
    }
  } else if (mode == 4){
    #pragma unroll
    for (int i = 0; i < 4; ++i){
      int row = rbase + i; if (row >= M) break;
      outF[(size_t)row*FD + n] = a[i] + bias0[n] + bias1[n];
    }
  } else { // mode 2
    float hv[4];
    const int omask = (1 << o_log2) - 1;
    #pragma unroll
    for (int i = 0; i < 4; ++i){
      int row = rbase + i;
      if (row >= M){ hv[i] = 0.f; continue; }
      float c = tanhf(a[i]);
      size_t off = (size_t)row*FD + n;
      float z = b2f(zb[off]);
      float s = b2f(sb[off]);
      float h = z*s + (1.f - z)*c;
      hv[i] = h;
      int tree = row >> o_log2, pos = row & omask;
      hO[((long)tree*NPT + o_start + pos)*FD + n] = f2b(h);
    }
    if (smode == 1){
      if (rbase + 1 < M) sN[(size_t)(rbase>>1)*FD + n] = f2b(hv[0] + hv[1]);
      if (rbase + 3 < M) sN[(size_t)((rbase>>1) + 1)*FD + n] = f2b(hv[2] + hv[3]);
    } else if (smode == 2){
      #pragma unroll
      for (int i = 0; i < 4; ++i){
        int row = rbase + i; if (row >= M) break;
        bf16 hb = f2b(hv[i]);
        sN[(size_t)(2*row)*FD + n] = hb;
        sN[(size_t)(2*row+1)*FD + n] = hb;
      }
    }
  }
}

// ---------------- big GEMM: 128x128 tile, BK=64, swizzled LDS ----------------
__global__ __launch_bounds__(256) void gemm_big(
    const bf16* __restrict__ A0, const bf16* __restrict__ A1,
    const bf16* __restrict__ Wp, int M, int K,
    int a_start, int a_log2, int o_start, int o_log2,
    const float* __restrict__ bias0, const float* __restrict__ bias1,
    const bf16* __restrict__ zb, const bf16* __restrict__ sb,
    bf16* __restrict__ o0, bf16* __restrict__ o1,
    bf16* __restrict__ hO, float* __restrict__ outF,
    bf16* __restrict__ sN, int smode, int mode)
{
  __shared__ bf16 As[128*64];
  __shared__ bf16 Bs[128*64];

  const int t = threadIdx.x, lane = t & 63, wid = t >> 6;
  const int wr = wid >> 1, wc = wid & 1;
  const int lr = lane & 15, quad = lane >> 4;
  const int m_blk = blockIdx.x*128, n_blk = blockIdx.y*128;
  const int Mm1 = M - 1;
  const int amask = (1 << a_log2) - 1;
  const int wbase = (t & ~63);

  f4v acc[4][4] = {};

  for (int k0 = 0; k0 < K; k0 += 64){
    // stage A (128 rows x 64 k), swizzled: chunk g stored at slot g^(row&7)
    #pragma unroll
    for (int p = 0; p < 4; ++p){
      int c = p*256 + t;
      int rl = c >> 3, slot = c & 7;
      int g = slot ^ (rl & 7);
      int kk = k0 + g*8;
      int r = m_blk + rl; if (r > Mm1) r = Mm1;
      const bf16* src;
      if (k0 < 512){
        int tr = r >> a_log2, po = r & amask;
        src = A0 + ((long)tr*NPT + a_start + po)*FD + kk;
      } else {
        src = A1 + (long)r*FD + (kk - 512);
      }
      gload_lds16(src, &As[(size_t)(p*256 + wbase)*8]);
    }
    // stage B
    #pragma unroll
    for (int p = 0; p < 4; ++p){
      int c = p*256 + t;
      int rl = c >> 3, slot = c & 7;
      int g = slot ^ (rl & 7);
      int kk = k0 + g*8;
      gload_lds16(Wp + (long)(n_blk + rl)*K + kk, &Bs[(size_t)(p*256 + wbase)*8]);
    }
    __syncthreads();

    #pragma unroll
    for (int kh = 0; kh < 2; ++kh){
      int cidx = kh*4 + quad;
      bf8v af[4], bv[4];
      #pragma unroll
      for (int i = 0; i < 4; ++i){
        int ra = wr*64 + i*16 + lr;
        af[i] = *(const bf8v*)&As[ra*64 + ((cidx ^ (ra & 7))*8)];
        int rb = wc*64 + i*16 + lr;
        bv[i] = *(const bf8v*)&Bs[rb*64 + ((cidx ^ (rb & 7))*8)];
      }
      #pragma unroll
      for (int i = 0; i < 4; ++i)
        #pragma unroll
        for (int j = 0; j < 4; ++j)
          acc[i][j] = __builtin_amdgcn_mfma_f32_16x16x32_bf16(af[i], bv[j], acc[i][j], 0, 0, 0);
    }
    __syncthreads();
  }

  #pragma unroll
  for (int mt = 0; mt < 4; ++mt){
    int rbase = m_blk + wr*64 + mt*16 + quad*4;
    #pragma unroll
    for (int nt = 0; nt < 4; ++nt){
      int n = n_blk + wc*64 + nt*16 + lr;
      epi4(acc[mt][nt], rbase, n, M, mode, bias0, bias1, zb, sb, o0, o1, hO, outF,
           o_start, o_log2, sN, smode);
    }
  }
}

// ---------------- small GEMM: 64x64 tile, direct loads, no barriers ----------------
__global__ __launch_bounds__(256) void gemm_small(
    const bf16* __restrict__ A0, const bf16* __restrict__ A1,
    const bf16* __restrict__ Wp, int M, int K,
    int a_start, int a_log2, int o_start, int o_log2,
    const float* __restrict__ bias0, const float* __restrict__ bias1,
    const bf16* __restrict__ zb, const bf16* __restrict__ sb,
    bf16* __restrict__ o0, bf16* __restrict__ o1,
    bf16* __restrict__ hO, float* __restrict__ outF,
    bf16* __restrict__ sN, int smode, int mode)
{
  const int lane = threadIdx.x & 63, wid = threadIdx.x >> 6;
  const int wr = wid >> 1, wc = wid & 1;
  const int m_base = blockIdx.x*64 + wr*32;
  const int n_base = blockIdx.y*64 + wc*32;
  const int lr = lane & 15, quad = lane >> 4;
  const int Mm1 = M - 1;
  const int amask = (1 << a_log2) - 1;

  f4v acc[2][2] = {};

  int am[2]; long arow[2];
  #pragma unroll
  for (int mt = 0; mt < 2; ++mt){
    int m = m_base + mt*16 + lr; if (m > Mm1) m = Mm1;
    am[mt] = m;
    int tree = m >> a_log2, pos = m & amask;
    arow[mt] = (long)tree*NPT + a_start + pos;
  }

  for (int k0 = 0; k0 < K; k0 += 32){
    int k = k0 + quad*8;
    bf8v a[2], b[2];
    #pragma unroll
    for (int mt = 0; mt < 2; ++mt){
      const bf16* p = (k0 < 512) ? (A0 + arow[mt]*FD + k)
                                 : (A1 + (long)am[mt]*FD + (k - 512));
      a[mt] = *(const bf8v*)p;
    }
    #pragma unroll
    for (int nt = 0; nt < 2; ++nt)
      b[nt] = *(const bf8v*)(Wp + (long)(n_base + nt*16 + lr)*K + k);
    #pragma unroll
    for (int mt = 0; mt < 2; ++mt)
      #pragma unroll
      for (int nt = 0; nt < 2; ++nt)
        acc[mt][nt] = __builtin_amdgcn_mfma_f32_16x16x32_bf16(a[mt], b[nt], acc[mt][nt], 0, 0, 0);
  }

  #pragma unroll
  for (int mt = 0; mt < 2; ++mt){
    int rbase = m_base + mt*16 + quad*4;
    #pragma unroll
    for (int nt = 0; nt < 2; ++nt){
      int n = n_base + nt*16 + lr;
      epi4(acc[mt][nt], rbase, n, M, mode, bias0, bias1, zb, sb, o0, o1, hO, outF,
           o_start, o_log2, sN, smode);
    }
  }
}

// ---------------- host launcher ----------------

extern "C" void kernel_launch(void* const* d_in, const int* in_sizes, int n_in,
                              void* d_out, int out_size, void* d_ws, size_t ws_size,
                              hipStream_t stream)
{
  const float* feat = (const float*)d_in[0];
  const float* Wh   = (const float*)d_in[1];
  const float* Wz   = (const float*)d_in[2];
  const float* Wr   = (const float*)d_in[3];
  const float* Uh   = (const float*)d_in[4];
  const float* Uz   = (const float*)d_in[5];
  const float* bUz  = (const float*)d_in[6];
  const float* Ur   = (const float*)d_in[7];
  const float* bUr  = (const float*)d_in[8];
  const float* Whd  = (const float*)d_in[9];
  const float* Wzd  = (const float*)d_in[10];
  const float* Wrd  = (const float*)d_in[11];
  const float* Uhd  = (const float*)d_in[12];
  const float* Uzd  = (const float*)d_in[13];
  const float* bUzd = (const float*)d_in[14];
  const float* Urd  = (const float*)d_in[15];
  const float* bUrd = (const float*)d_in[16];
  const float* W1   = (const float*)d_in[17];
  const float* b1   = (const float*)d_in[18];
  const float* W2   = (const float*)d_in[19];
  const float* b2   = (const float*)d_in[20];
  float* out = (float*)d_out;

  int starts[12], szs[12];
  { int s = 0, sz = 2048; for (int l = 0; l < 12; ++l){ starts[l] = s; szs[l] = sz; s += sz; sz >>= 1; } }

  char* p = (char*)d_ws;
  auto take = [&](size_t b)->char*{ char* q = p; p += (b + 255) & ~(size_t)255; return q; };
  bf16* featb = (bf16*)take((size_t)NT*FD*2);
  bf16* h_b   = (bf16*)take((size_t)NT*FD*2);
  bf16* hd_b  = (bf16*)take((size_t)NT*FD*2);
  bf16* Wl    = (bf16*)take((size_t)1024*512*2);
  bf16* Wzr_u = (bf16*)take((size_t)1024*1024*2);
  bf16* Whu   = (bf16*)take((size_t)512*1024*2);
  bf16* Wzr_d = (bf16*)take((size_t)1024*1024*2);
  bf16* Whu_d = (bf16*)take((size_t)512*1024*2);
  bf16* Wout  = (bf16*)take((size_t)512*1024*2);
  bf16* z16   = (bf16*)take((size_t)16384*512*2);
  bf16* t16   = (bf16*)take((size_t)16384*512*2);
  bf16* rh16  = (bf16*)take((size_t)16384*512*2);
  bf16* sP0   = (bf16*)take((size_t)16384*512*2);
  bf16* sP1   = (bf16*)take((size_t)16384*512*2);
  if ((size_t)(p - (char*)d_ws) > ws_size) return;

  // --- stage inputs: 2 launches ---
  cvt_b16<<<(NT*FD/8 + 255)/256, 256, 0, stream>>>(featb, feat, NT*FD/8);
  PackArgs pa;
  int pi = 0;
  auto pk = [&](const float* src, bf16* dst, int dk, int ro, int co){
    pa.s[pi] = src; pa.d[pi] = dst; pa.dk[pi] = dk; pa.ro[pi] = ro; pa.co[pi] = co; ++pi;
  };
  pk(Wz, Wl, 512, 0, 0);     pk(Wh, Wl, 512, 512, 0);
  pk(Wz, Wzr_u, 1024, 0, 0); pk(Uz, Wzr_u, 1024, 0, 512);
  pk(Wr, Wzr_u, 1024, 512, 0); pk(Ur, Wzr_u, 1024, 512, 512);
  pk(Wh, Whu, 1024, 0, 0);   pk(Uh, Whu, 1024, 0, 512);
  pk(Wzd, Wzr_d, 1024, 0, 0); pk(Uzd, Wzr_d, 1024, 0, 512);
  pk(Wrd, Wzr_d, 1024, 512, 0); pk(Urd, Wzr_d, 1024, 512, 512);
  pk(Whd, Whu_d, 1024, 0, 0); pk(Uhd, Whu_d, 1024, 0, 512);
  pk(W1, Wout, 1024, 0, 0);  pk(W2, Wout, 1024, 0, 512);
  pack_all<<<2048, 256, 0, stream>>>(pa);

  auto gemm = [&](const bf16* A0, const bf16* A1, const bf16* Wp, int M, int N, int K,
                  int a_start, int a_log2, int o_start, int o_log2,
                  const float* bias0, const float* bias1,
                  const bf16* zb, const bf16* sb,
                  bf16* o0, bf16* o1, bf16* hO, float* outF,
                  bf16* sN, int smode, int mode){
    if (M >= 512){
      dim3 g((M + 127)/128, N/128);
      gemm_big<<<g, 256, 0, stream>>>(A0, A1, Wp, M, K, a_start, a_log2, o_start, o_log2,
                                      bias0, bias1, zb, sb, o0, o1, hO, outF, sN, smode, mode);
    } else {
      dim3 g((M + 63)/64, N/64);
      gemm_small<<<g, 256, 0, stream>>>(A0, A1, Wp, M, K, a_start, a_log2, o_start, o_log2,
                                        bias0, bias1, zb, sb, o0, o1, hO, outF, sN, smode, mode);
    }
  };

  // --- leaves: z -> z16, t -> t16 (mode 0), then combine + pair-sum into sP0 ---
  gemm(featb, nullptr, Wl, 16384, 1024, 512, 0, 11, 0, 0,
       nullptr, nullptr, nullptr, nullptr, z16, t16, nullptr, nullptr, nullptr, 0, 0);
  leaf_combine<<<2048, 256, 0, stream>>>(h_b, sP0, z16, t16);

  // --- bottom-up: level l reads s=sP[l%2], cand writes sP[(l+1)%2] ---
  for (int l = 0; l < 11; ++l){
    int Mf = 8*szs[l+1];
    int al2 = 10 - l;
    bf16* sCur = (l & 1) ? sP1 : sP0;
    bf16* sNext = (l & 1) ? sP0 : sP1;
    int smode = (l < 10) ? 1 : 0;
    gemm(featb, sCur, Wzr_u, Mf, 1024, 1024, starts[l+1], al2, 0, 0,
         bUz, bUr, nullptr, sCur, z16, rh16, nullptr, nullptr, nullptr, 0, 1);
    gemm(featb, rh16, Whu, Mf, 512, 1024, starts[l+1], al2, starts[l+1], al2,
         nullptr, nullptr, z16, sCur, nullptr, nullptr, h_b, nullptr, sNext, smode, 2);
  }

  // --- roots: hd=h at roots; broadcast into sP0 rows 0..15 ---
  roots_k<<<2, 256, 0, stream>>>(hd_b, sP0, h_b);

  // --- top-down: level l (10..0) reads sP[(10-l)%2], cand writes other ---
  for (int l = 10; l >= 0; --l){
    int Ms = 8*szs[l];
    int al2 = 11 - l;
    bf16* sCur = ((10 - l) & 1) ? sP1 : sP0;
    bf16* sNext = ((10 - l) & 1) ? sP0 : sP1;
    int smode = (l > 0) ? 2 : 0;
    gemm(featb, sCur, Wzr_d, Ms, 1024, 1024, starts[l], al2, 0, 0,
         bUzd, bUrd, nullptr, sCur, z16, rh16, nullptr, nullptr, nullptr, 0, 1);
    gemm(featb, rh16, Whu_d, Ms, 512, 1024, starts[l], al2, starts[l], al2,
         nullptr, nullptr, z16, sCur, nullptr, nullptr, hd_b, nullptr, sNext, smode, 2);
  }

  // --- output: [h|hd] @ [W1|W2].T + b1 + b2 ---
  gemm(h_b, hd_b, Wout, NT, 512, 1024, 0, 26, 0, 26,
       b1, b2, nullptr, nullptr, nullptr, nullptr, nullptr, out, nullptr, 0, 4);
}